// Round 2
// baseline (396.271 us; speedup 1.0000x reference)
//
#include <hip/hip_runtime.h>
#include <hip/hip_bf16.h>

#define N_NODES 50000
#define E_EDGES 800000
#define S_SAMP 4
#define D_DIM 24
#define NS (N_NODES * S_SAMP)   // 200000

// workspace layout (float offsets) — total 5,600,512 floats = 22.4 MB
#define OFF_AGGX  0                 // N*16 = 800000
#define OFF_AGGC  800000            // N*32 = 1600000
#define OFF_STATS 2400000           // 512 floats
// stats: [0:64) sum_s [64:128) sq_s [128:192) sum_a [192:256) sq_a
//        [256:320) scale_s [320:384) shift_s [384:448) scale_a [448:512) shift_a
#define OFF_MA    2400512           // N*64 = 3200000

// ---------------------------------------------------------------------------
// Edge scatter: 48 unique columns per node (x-part identical across samples)
// ---------------------------------------------------------------------------
__global__ __launch_bounds__(256) void scatter_kernel(
    const float* __restrict__ x,
    const float* __restrict__ c,
    const int* __restrict__ ei,
    float* __restrict__ aggx,
    float* __restrict__ aggc)
{
    long long t = (long long)blockIdx.x * blockDim.x + threadIdx.x;
    if (t >= (long long)E_EDGES * 48) return;
    int e = (int)(t / 48);
    int k = (int)(t % 48);
    int src = ei[e];
    int dst = ei[E_EDGES + e];
    if (k < 16) {
        atomicAdd(&aggx[dst * 16 + k], x[src * 16 + k]);
    } else {
        int kk = k - 16;
        atomicAdd(&aggc[dst * 32 + kk], c[src * 32 + kk]);
    }
}

// ---------------------------------------------------------------------------
// Stats pass (shared/siamese path): rows = N*S. z1 = m @ W1s + b1s; accumulate
// per-column sum/sumsq only (z1 recomputed in pass 2).
// ---------------------------------------------------------------------------
__global__ __launch_bounds__(256) void stats_shared_kernel(
    const float* __restrict__ x,
    const float* __restrict__ c,
    const float* __restrict__ aggx,
    const float* __restrict__ aggc,
    const float* __restrict__ w1,
    const float* __restrict__ b1,
    const float* __restrict__ epsp,
    float* __restrict__ stats)
{
    __shared__ float sM[256][28];
    __shared__ float sRed[8][64];

    const int tid = threadIdx.x;
    const float eps1 = 1.0f + epsp[0];
    const int r0 = blockIdx.x * 256;
    const int row = r0 + tid;

    if (row < NS) {
        const int n = row >> 2;
        const int s = row & 3;
        const float* xr = x + n * 16;
        const float* ax = aggx + n * 16;
#pragma unroll
        for (int j = 0; j < 16; ++j)
            sM[tid][j] = fmaf(eps1, xr[j], ax[j]);
        const float* cr = c + n * 32 + s * 8;
        const float* ac = aggc + n * 32 + s * 8;
#pragma unroll
        for (int kk = 0; kk < 8; ++kk)
            sM[tid][16 + kk] = fmaf(eps1, cr[kk], ac[kk]);
    }

    const int e = tid & 63;
    const int rg = tid >> 6;
    float wreg[D_DIM];
#pragma unroll
    for (int j = 0; j < D_DIM; ++j)
        wreg[j] = w1[j * 64 + e];
    const float bb = b1[e];

    __syncthreads();

    float lsum = 0.f, lsq = 0.f;
    for (int r = rg; r < 256; r += 4) {
        int rw = r0 + r;
        if (rw >= NS) break;
        float acc = bb;
#pragma unroll
        for (int j = 0; j < D_DIM; ++j)
            acc = fmaf(sM[r][j], wreg[j], acc);
        lsum += acc;
        lsq = fmaf(acc, acc, lsq);
    }
    sRed[rg][e] = lsum;
    sRed[4 + rg][e] = lsq;
    __syncthreads();
    if (rg == 0) {
        float ts = sRed[0][e] + sRed[1][e] + sRed[2][e] + sRed[3][e];
        float tq = sRed[4][e] + sRed[5][e] + sRed[6][e] + sRed[7][e];
        atomicAdd(&stats[e], ts);
        atomicAdd(&stats[64 + e], tq);
    }
}

// ---------------------------------------------------------------------------
// Stats pass (aggregated/mean path): rows = N
// ---------------------------------------------------------------------------
__global__ __launch_bounds__(256) void stats_agg_kernel(
    const float* __restrict__ x,
    const float* __restrict__ c,
    const float* __restrict__ aggx,
    const float* __restrict__ aggc,
    const float* __restrict__ w1,
    const float* __restrict__ b1,
    const float* __restrict__ epsp,
    float* __restrict__ stats)
{
    __shared__ float sM[256][28];
    __shared__ float sRed[8][64];

    const int tid = threadIdx.x;
    const float eps1 = 1.0f + epsp[0];
    const int r0 = blockIdx.x * 256;
    const int row = r0 + tid;

    if (row < N_NODES) {
        const int n = row;
        const float* xr = x + n * 16;
        const float* ax = aggx + n * 16;
#pragma unroll
        for (int j = 0; j < 16; ++j)
            sM[tid][j] = fmaf(eps1, xr[j], ax[j]);
        const float* cr = c + n * 32;
        const float* ac = aggc + n * 32;
#pragma unroll
        for (int kk = 0; kk < 8; ++kk) {
            float sc = 0.f, sa = 0.f;
#pragma unroll
            for (int s = 0; s < 4; ++s) {
                sc += cr[s * 8 + kk];
                sa += ac[s * 8 + kk];
            }
            sM[tid][16 + kk] = 0.25f * fmaf(eps1, sc, sa);
        }
    }

    const int e = tid & 63;
    const int rg = tid >> 6;
    float wreg[D_DIM];
#pragma unroll
    for (int j = 0; j < D_DIM; ++j)
        wreg[j] = w1[j * 64 + e];
    const float bb = b1[e];

    __syncthreads();

    float lsum = 0.f, lsq = 0.f;
    for (int r = rg; r < 256; r += 4) {
        int rw = r0 + r;
        if (rw >= N_NODES) break;
        float acc = bb;
#pragma unroll
        for (int j = 0; j < D_DIM; ++j)
            acc = fmaf(sM[r][j], wreg[j], acc);
        lsum += acc;
        lsq = fmaf(acc, acc, lsq);
    }
    sRed[rg][e] = lsum;
    sRed[4 + rg][e] = lsq;
    __syncthreads();
    if (rg == 0) {
        float ts = sRed[0][e] + sRed[1][e] + sRed[2][e] + sRed[3][e];
        float tq = sRed[4][e] + sRed[5][e] + sRed[6][e] + sRed[7][e];
        atomicAdd(&stats[128 + e], ts);
        atomicAdd(&stats[192 + e], tq);
    }
}

// ---------------------------------------------------------------------------
// Finalize BN statistics -> per-column scale/shift for both paths
// ---------------------------------------------------------------------------
__global__ void bn_finalize_kernel(
    float* __restrict__ stats,
    const float* __restrict__ g1s,
    const float* __restrict__ be1s,
    const float* __restrict__ g1a,
    const float* __restrict__ be1a)
{
    int tid = threadIdx.x;
    if (tid >= 128) return;
    int e = tid & 63;
    int p = tid >> 6;
    float cnt = p ? (float)N_NODES : (float)NS;
    float su = stats[p * 128 + e];
    float sq = stats[p * 128 + 64 + e];
    float mu = su / cnt;
    float var = sq / cnt - mu * mu;
    float rstd = rsqrtf(var + 1e-5f);
    float g = p ? g1a[e] : g1s[e];
    float b = p ? be1a[e] : be1s[e];
    float sc = g * rstd;
    stats[256 + p * 128 + e] = sc;
    stats[256 + p * 128 + 64 + e] = fmaf(-mu, sc, b);
}

// ---------------------------------------------------------------------------
// Pass 2 (agg path): recompute z1a, bn+relu, @W2a + b2a -> ma [N,64] fp32
// 64 rows per block, 256 threads.
// ---------------------------------------------------------------------------
__global__ __launch_bounds__(256) void mlp2_agg_kernel(
    const float* __restrict__ x,
    const float* __restrict__ c,
    const float* __restrict__ aggx,
    const float* __restrict__ aggc,
    const float* __restrict__ w1,
    const float* __restrict__ b1,
    const float* __restrict__ epsp,
    const float* __restrict__ stats,
    const float* __restrict__ w2,
    const float* __restrict__ b2,
    float* __restrict__ ma)
{
    __shared__ float sM[64][28];
    __shared__ float sH[64 * 64];

    const int tid = threadIdx.x;
    const float eps1 = 1.0f + epsp[0];
    const int r0 = blockIdx.x * 64;
    const float* scale = stats + 384;
    const float* shift = stats + 448;

    // build m rows (element-distributed)
    for (int i = tid; i < 64 * 24; i += 256) {
        int r = i / 24, j = i % 24;
        int n = r0 + r;
        float v = 0.f;
        if (n < N_NODES) {
            if (j < 16) {
                v = fmaf(eps1, x[n * 16 + j], aggx[n * 16 + j]);
            } else {
                int kk = j - 16;
                float sc = 0.f, sa = 0.f;
#pragma unroll
                for (int s = 0; s < 4; ++s) {
                    sc += c[n * 32 + s * 8 + kk];
                    sa += aggc[n * 32 + s * 8 + kk];
                }
                v = 0.25f * fmaf(eps1, sc, sa);
            }
        }
        sM[r][j] = v;
    }

    const int e = tid & 63;
    const int rg = tid >> 6;

    __syncthreads();

    // matmul1 + bn + relu -> sH
    {
        float w1reg[D_DIM];
#pragma unroll
        for (int j = 0; j < D_DIM; ++j)
            w1reg[j] = w1[j * 64 + e];
        const float b1e = b1[e];
        const float sce = scale[e], she = shift[e];
        for (int r = rg; r < 64; r += 4) {
            float acc = b1e;
#pragma unroll
            for (int j = 0; j < D_DIM; ++j)
                acc = fmaf(sM[r][j], w1reg[j], acc);
            sH[r * 64 + e] = fmaxf(fmaf(acc, sce, she), 0.f);
        }
    }
    __syncthreads();

    // matmul2 -> ma
    {
        float w2reg[64];
#pragma unroll
        for (int k = 0; k < 64; ++k)
            w2reg[k] = w2[k * 64 + e];
        const float b2e = b2[e];
        for (int r = rg; r < 64; r += 4) {
            int rw = r0 + r;
            if (rw >= N_NODES) break;
            float acc = b2e;
#pragma unroll
            for (int k = 0; k < 64; ++k)
                acc = fmaf(sH[r * 64 + k], w2reg[k], acc);
            ma[rw * 64 + e] = acc;
        }
    }
}

// ---------------------------------------------------------------------------
// Pass 2 (shared path) + DSS combine: recompute z1s, bn+relu, @W2s + b2s
// + ma[n] -> out [NS,64] fp32
// ---------------------------------------------------------------------------
__global__ __launch_bounds__(256) void mlp2_shared_kernel(
    const float* __restrict__ x,
    const float* __restrict__ c,
    const float* __restrict__ aggx,
    const float* __restrict__ aggc,
    const float* __restrict__ w1,
    const float* __restrict__ b1,
    const float* __restrict__ epsp,
    const float* __restrict__ stats,
    const float* __restrict__ w2,
    const float* __restrict__ b2,
    const float* __restrict__ ma,
    float* __restrict__ out)
{
    __shared__ float sM[64][28];
    __shared__ float sH[64 * 64];

    const int tid = threadIdx.x;
    const float eps1 = 1.0f + epsp[0];
    const int r0 = blockIdx.x * 64;
    const float* scale = stats + 256;
    const float* shift = stats + 320;

    for (int i = tid; i < 64 * 24; i += 256) {
        int r = i / 24, j = i % 24;
        int rw = r0 + r;
        float v = 0.f;
        if (rw < NS) {
            int n = rw >> 2;
            int s = rw & 3;
            if (j < 16) {
                v = fmaf(eps1, x[n * 16 + j], aggx[n * 16 + j]);
            } else {
                int kk = j - 16;
                v = fmaf(eps1, c[n * 32 + s * 8 + kk], aggc[n * 32 + s * 8 + kk]);
            }
        }
        sM[r][j] = v;
    }

    const int e = tid & 63;
    const int rg = tid >> 6;

    __syncthreads();

    {
        float w1reg[D_DIM];
#pragma unroll
        for (int j = 0; j < D_DIM; ++j)
            w1reg[j] = w1[j * 64 + e];
        const float b1e = b1[e];
        const float sce = scale[e], she = shift[e];
        for (int r = rg; r < 64; r += 4) {
            float acc = b1e;
#pragma unroll
            for (int j = 0; j < D_DIM; ++j)
                acc = fmaf(sM[r][j], w1reg[j], acc);
            sH[r * 64 + e] = fmaxf(fmaf(acc, sce, she), 0.f);
        }
    }
    __syncthreads();

    {
        float w2reg[64];
#pragma unroll
        for (int k = 0; k < 64; ++k)
            w2reg[k] = w2[k * 64 + e];
        const float b2e = b2[e];
        for (int r = rg; r < 64; r += 4) {
            int rw = r0 + r;
            if (rw >= NS) break;
            float acc = b2e + ma[(rw >> 2) * 64 + e];
#pragma unroll
            for (int k = 0; k < 64; ++k)
                acc = fmaf(sH[r * 64 + k], w2reg[k], acc);
            out[rw * 64 + e] = acc;
        }
    }
}

// ---------------------------------------------------------------------------
extern "C" void kernel_launch(void* const* d_in, const int* in_sizes, int n_in,
                              void* d_out, int out_size, void* d_ws, size_t ws_size,
                              hipStream_t stream)
{
    const float* x    = (const float*)d_in[0];
    const float* c    = (const float*)d_in[1];
    const int*   ei   = (const int*)d_in[2];
    const float* epsS = (const float*)d_in[3];
    const float* W1s  = (const float*)d_in[4];
    const float* b1s  = (const float*)d_in[5];
    const float* g1s  = (const float*)d_in[6];
    const float* be1s = (const float*)d_in[7];
    const float* W2s  = (const float*)d_in[8];
    const float* b2s  = (const float*)d_in[9];
    const float* epsA = (const float*)d_in[10];
    const float* W1a  = (const float*)d_in[11];
    const float* b1a  = (const float*)d_in[12];
    const float* g1a  = (const float*)d_in[13];
    const float* be1a = (const float*)d_in[14];
    const float* W2a  = (const float*)d_in[15];
    const float* b2a  = (const float*)d_in[16];

    float* ws    = (float*)d_ws;
    float* aggx  = ws + OFF_AGGX;
    float* aggc  = ws + OFF_AGGC;
    float* stats = ws + OFF_STATS;
    float* ma    = ws + OFF_MA;

    // zero agg buffers + stats (ws is poisoned each call)
    hipMemsetAsync(d_ws, 0, (size_t)(OFF_STATS + 512) * sizeof(float), stream);

    {
        long long total = (long long)E_EDGES * 48;
        int blocks = (int)((total + 255) / 256);
        scatter_kernel<<<blocks, 256, 0, stream>>>(x, c, ei, aggx, aggc);
    }

    stats_shared_kernel<<<(NS + 255) / 256, 256, 0, stream>>>(
        x, c, aggx, aggc, W1s, b1s, epsS, stats);
    stats_agg_kernel<<<(N_NODES + 255) / 256, 256, 0, stream>>>(
        x, c, aggx, aggc, W1a, b1a, epsA, stats);

    bn_finalize_kernel<<<1, 128, 0, stream>>>(stats, g1s, be1s, g1a, be1a);

    mlp2_agg_kernel<<<(N_NODES + 63) / 64, 256, 0, stream>>>(
        x, c, aggx, aggc, W1a, b1a, epsA, stats, W2a, b2a, ma);

    mlp2_shared_kernel<<<(NS + 63) / 64, 256, 0, stream>>>(
        x, c, aggx, aggc, W1s, b1s, epsS, stats, W2s, b2s, ma, (float*)d_out);
}